// Round 2
// baseline (5220.868 us; speedup 1.0000x reference)
//
#include <hip/hip_runtime.h>
#include <math.h>

#define NB 256      // events
#define NSV 64
#define NTRK 512
#define NPFC 512
#define KNN 8
#define HD 32

__device__ __forceinline__ float elu_f(float x) {
    return x > 0.f ? x : __expf(x) - 1.f;
}

// ---------------- encoder: out = elu(elu(x@W1+b1)@W2+b2) ----------------
// 32 nodes per block (4 iterations of 8), weights staged once.
template<int FIN>
__global__ __launch_bounds__(256) void encode_kernel(
    const float* __restrict__ x, const float* __restrict__ W1, const float* __restrict__ b1,
    const float* __restrict__ W2, const float* __restrict__ b2,
    float* __restrict__ out, int n_nodes)
{
    __shared__ float sW1[FIN * 32];
    __shared__ float sW2[32 * 32];
    __shared__ float sb1[32], sb2[32];
    __shared__ float sx[8][FIN];
    __shared__ float sh[8][32];
    int tid = threadIdx.x;
    for (int i = tid; i < FIN * 32; i += 256) sW1[i] = W1[i];
    for (int i = tid; i < 32 * 32; i += 256) sW2[i] = W2[i];
    if (tid < 32) { sb1[tid] = b1[tid]; sb2[tid] = b2[tid]; }
    int ln = tid >> 5, c = tid & 31;
    for (int it = 0; it < 4; it++) {
        int node0 = blockIdx.x * 32 + it * 8;
        __syncthreads();
        for (int i = tid; i < 8 * FIN; i += 256) {
            int nn = i / FIN, f = i - nn * FIN;
            int node = node0 + nn;
            sx[nn][f] = (node < n_nodes) ? x[(size_t)node * FIN + f] : 0.f;
        }
        __syncthreads();
        float h = sb1[c];
#pragma unroll
        for (int f = 0; f < FIN; f++) h = fmaf(sx[ln][f], sW1[f * 32 + c], h);
        h = elu_f(h);
        sh[ln][c] = h;
        __syncthreads();
        float o = sb2[c];
#pragma unroll
        for (int k = 0; k < 32; k++) o = fmaf(sh[ln][k], sW2[k * 32 + c], o);
        o = elu_f(o);
        int node = node0 + ln;
        if (node < n_nodes) out[(size_t)node * 32 + c] = o;
    }
}

// ---------------- weight prep: Wd = W[0:32]-W[32:64], W2h = W[32:64] ----------------
__global__ void prep_w_kernel(const float* __restrict__ W, const float* __restrict__ b,
                              float* __restrict__ wd, float* __restrict__ w2h,
                              float* __restrict__ bb)
{
    int i = threadIdx.x + blockIdx.x * blockDim.x;
    if (i < 1024) {
        float lo = W[i], hi = W[1024 + i];
        wd[i] = lo - hi;
        w2h[i] = hi;
    }
    if (i < 32) bb[i] = b[i];
}

// top-8 smallest across (lane, j) candidates; tie-break on lower src index.
template<int NJ>
__device__ __forceinline__ void top8_sel(float* dv, int lane, int* sel) {
#pragma unroll
    for (int k = 0; k < KNN; k++) {
        float bv = dv[0]; int bj = 0;
#pragma unroll
        for (int j = 1; j < NJ; j++) if (dv[j] < bv) { bv = dv[j]; bj = j; }
        int bs = lane + 64 * bj;
#pragma unroll
        for (int off = 32; off >= 1; off >>= 1) {
            float ov = __shfl_down(bv, off);
            int   os = __shfl_down(bs, off);
            if (ov < bv || (ov == bv && os < bs)) { bv = ov; bs = os; }
        }
        bs = __shfl(bs, 0);
        sel[k] = bs;
#pragma unroll
        for (int j = 0; j < NJ; j++) if (bs == lane + 64 * j) dv[j] = 1e30f;
    }
}

// ---------------- edge conv: kNN(K=8) + edge MLP + max-agg ----------------
// src [B,NS,32], dst [B,512,32], out [B,512,32]
// One block = (event, half of dst). 4 waves; each wave processes 2 dst nodes
// per pass (amortizes src LDS reads). LDS layout is float4-quad XOR-swizzled:
// quad q of row s lives at s_src[s*8 + (q ^ (s&7))] -> bank-optimal b128.
template<int NS>
__global__ __launch_bounds__(256, 2) void edgeconv_kernel(
    const float* __restrict__ src, const float* __restrict__ dst,
    const float* __restrict__ Wd, const float* __restrict__ W2h,
    const float* __restrict__ bias, float* __restrict__ out)
{
    constexpr int NJ = NS / 64;
    __shared__ float4 s_src[NS * 8];
    int b  = blockIdx.x >> 1;
    int hb = blockIdx.x & 1;
    int tid = threadIdx.x;
    int lane = tid & 63;
    int wave = tid >> 6;

    const float4* src4 = (const float4*)(src + (size_t)b * NS * 32);
    for (int i = tid; i < NS * 8; i += 256) {
        int s = i >> 3, q = i & 7;
        s_src[s * 8 + (q ^ (s & 7))] = src4[i];
    }
    __syncthreads();

    // per-lane weight columns for c = lane&31 (registers; budget is 256 VGPRs
    // at 2 waves/EU, LDS is the occupancy limiter anyway)
    int c = lane & 31;
    float wdr[32], w2r[32];
#pragma unroll
    for (int d = 0; d < 32; d++) { wdr[d] = Wd[d * 32 + c]; w2r[d] = W2h[d * 32 + c]; }
    float bc = bias[c];
    int hsel = lane >> 5;

    // per-lane row norms (ascending-d fma chain, matches ref tie structure)
    float nrm[NJ];
#pragma unroll
    for (int j = 0; j < NJ; j++) {
        int s = lane + 64 * j;
        float a = 0.f;
#pragma unroll
        for (int q = 0; q < 8; q++) {
            float4 v = s_src[s * 8 + (q ^ (s & 7))];
            a = fmaf(v.x, v.x, a); a = fmaf(v.y, v.y, a);
            a = fmaf(v.z, v.z, a); a = fmaf(v.w, v.w, a);
        }
        nrm[j] = a;
    }

    for (int t0 = wave * 2; t0 < 256; t0 += 8) {
        int tA = hb * 256 + t0;
        int tB = tA + 1;
        const float4* xiA = (const float4*)(dst + ((size_t)b * 512 + tA) * 32);
        const float4* xiB = xiA + 8;

        float dotA[NJ], dotB[NJ];
#pragma unroll
        for (int j = 0; j < NJ; j++) { dotA[j] = 0.f; dotB[j] = 0.f; }
        float baseA = bc, baseB = bc;

#pragma unroll
        for (int q = 0; q < 8; q++) {
            float4 a4 = xiA[q];
            float4 b4 = xiB[q];
            baseA = fmaf(a4.x, wdr[q*4+0], baseA); baseA = fmaf(a4.y, wdr[q*4+1], baseA);
            baseA = fmaf(a4.z, wdr[q*4+2], baseA); baseA = fmaf(a4.w, wdr[q*4+3], baseA);
            baseB = fmaf(b4.x, wdr[q*4+0], baseB); baseB = fmaf(b4.y, wdr[q*4+1], baseB);
            baseB = fmaf(b4.z, wdr[q*4+2], baseB); baseB = fmaf(b4.w, wdr[q*4+3], baseB);
#pragma unroll
            for (int j = 0; j < NJ; j++) {
                int s = lane + 64 * j;
                float4 v = s_src[s * 8 + (q ^ (s & 7))];
                dotA[j] = fmaf(a4.x, v.x, dotA[j]); dotA[j] = fmaf(a4.y, v.y, dotA[j]);
                dotA[j] = fmaf(a4.z, v.z, dotA[j]); dotA[j] = fmaf(a4.w, v.w, dotA[j]);
                dotB[j] = fmaf(b4.x, v.x, dotB[j]); dotB[j] = fmaf(b4.y, v.y, dotB[j]);
                dotB[j] = fmaf(b4.z, v.z, dotB[j]); dotB[j] = fmaf(b4.w, v.w, dotB[j]);
            }
        }
        float dvA[NJ], dvB[NJ];
#pragma unroll
        for (int j = 0; j < NJ; j++) {
            dvA[j] = nrm[j] - 2.f * dotA[j];
            dvB[j] = nrm[j] - 2.f * dotB[j];
        }

        int selA[KNN], selB[KNN];
        top8_sel<NJ>(dvA, lane, selA);
        top8_sel<NJ>(dvB, lane, selB);

        // edge MLP + max-agg for dst A
        {
            float mx = -1e30f;
#pragma unroll
            for (int p = 0; p < 4; p++) {
                int r = hsel ? selA[2*p+1] : selA[2*p];
                float acc = baseA;
#pragma unroll
                for (int q = 0; q < 8; q++) {
                    float4 v = s_src[r * 8 + (q ^ (r & 7))];
                    acc = fmaf(v.x, w2r[q*4+0], acc); acc = fmaf(v.y, w2r[q*4+1], acc);
                    acc = fmaf(v.z, w2r[q*4+2], acc); acc = fmaf(v.w, w2r[q*4+3], acc);
                }
                mx = fmaxf(mx, elu_f(acc));
            }
            mx = fmaxf(mx, __shfl_xor(mx, 32));
            if (lane < 32) out[((size_t)b * 512 + tA) * 32 + c] = mx;
        }
        // edge MLP + max-agg for dst B
        {
            float mx = -1e30f;
#pragma unroll
            for (int p = 0; p < 4; p++) {
                int r = hsel ? selB[2*p+1] : selB[2*p];
                float acc = baseB;
#pragma unroll
                for (int q = 0; q < 8; q++) {
                    float4 v = s_src[r * 8 + (q ^ (r & 7))];
                    acc = fmaf(v.x, w2r[q*4+0], acc); acc = fmaf(v.y, w2r[q*4+1], acc);
                    acc = fmaf(v.z, w2r[q*4+2], acc); acc = fmaf(v.w, w2r[q*4+3], acc);
                }
                mx = fmaxf(mx, elu_f(acc));
            }
            mx = fmaxf(mx, __shfl_xor(mx, 32));
            if (lane < 32) out[((size_t)b * 512 + tB) * 32 + c] = mx;
        }
    }
}

// ---------------- mean pool + out MLP + sigmoid + arange ----------------
__global__ __launch_bounds__(64) void final_kernel(
    const float* __restrict__ f3,
    const float* __restrict__ W1, const float* __restrict__ b1,
    const float* __restrict__ W2, const float* __restrict__ b2,
    float* __restrict__ outp)
{
    int b = blockIdx.x;
    int lane = threadIdx.x;
    int c = lane & 31, hh = lane >> 5;
    const float* base = f3 + (size_t)b * 512 * 32;
    float s = 0.f;
    for (int r = hh; r < 512; r += 2) s += base[r * 32 + c];
    s += __shfl_xor(s, 32);
    float pooled = s * (1.0f / 512.0f);
    __shared__ float sp[32];
    __shared__ float sh1[32];
    if (lane < 32) sp[c] = pooled;
    __syncthreads();
    if (lane < 32) {
        float h = b1[c];
#pragma unroll
        for (int d = 0; d < 32; d++) h = fmaf(sp[d], W1[d * 32 + c], h);
        sh1[c] = elu_f(h);
    }
    __syncthreads();
    if (lane == 0) {
        float o = b2[0];
#pragma unroll
        for (int d = 0; d < 32; d++) o = fmaf(sh1[d], W2[d], o);
        o = 1.f / (1.f + __expf(-o));
        outp[b] = o;                 // output 0: sigmoid [B,1]
        outp[NB + b] = (float)b;     // output 1: arange(B) read as float
    }
}

extern "C" void kernel_launch(void* const* d_in, const int* in_sizes, int n_in,
                              void* d_out, int out_size, void* d_ws, size_t ws_size,
                              hipStream_t stream) {
    const float* x_sv  = (const float*)d_in[0];
    const float* x_trk = (const float*)d_in[1];
    const float* x_pfc = (const float*)d_in[2];
    const float* sv_W1  = (const float*)d_in[6];
    const float* sv_b1  = (const float*)d_in[7];
    const float* sv_W2  = (const float*)d_in[8];
    const float* sv_b2  = (const float*)d_in[9];
    const float* trk_W1 = (const float*)d_in[10];
    const float* trk_b1 = (const float*)d_in[11];
    const float* trk_W2 = (const float*)d_in[12];
    const float* trk_b2 = (const float*)d_in[13];
    const float* pfc_W1 = (const float*)d_in[14];
    const float* pfc_b1 = (const float*)d_in[15];
    const float* pfc_W2 = (const float*)d_in[16];
    const float* pfc_b2 = (const float*)d_in[17];
    const float* conv_W = (const float*)d_in[18];
    const float* conv_b = (const float*)d_in[19];
    const float* out_W1 = (const float*)d_in[20];
    const float* out_b1 = (const float*)d_in[21];
    const float* out_W2 = (const float*)d_in[22];
    const float* out_b2 = (const float*)d_in[23];

    float* ws = (float*)d_ws;
    const size_t SV_E  = (size_t)NB * NSV * HD;
    const size_t TRK_E = (size_t)NB * NTRK * HD;
    float* sv_enc  = ws;
    float* trk_enc = sv_enc + SV_E;
    float* pfc_enc = trk_enc + TRK_E;
    float* f1      = pfc_enc + TRK_E;
    float* f2      = f1 + TRK_E;
    float* wd      = f2 + TRK_E;
    float* w2h     = wd + 1024;
    float* bb      = w2h + 1024;
    float* f3      = trk_enc;  // trk_enc dead after conv2 -> reuse

    prep_w_kernel<<<1, 1024, 0, stream>>>(conv_W, conv_b, wd, w2h, bb);

    encode_kernel<14><<<(NB * NSV) / 32, 256, 0, stream>>>(x_sv, sv_W1, sv_b1, sv_W2, sv_b2, sv_enc, NB * NSV);
    encode_kernel<30><<<(NB * NTRK) / 32, 256, 0, stream>>>(x_trk, trk_W1, trk_b1, trk_W2, trk_b2, trk_enc, NB * NTRK);
    encode_kernel<10><<<(NB * NPFC) / 32, 256, 0, stream>>>(x_pfc, pfc_W1, pfc_b1, pfc_W2, pfc_b2, pfc_enc, NB * NPFC);

    edgeconv_kernel<64> <<<NB * 2, 256, 0, stream>>>(sv_enc,  trk_enc, wd, w2h, bb, f1);
    edgeconv_kernel<512><<<NB * 2, 256, 0, stream>>>(pfc_enc, trk_enc, wd, w2h, bb, f2);
    edgeconv_kernel<512><<<NB * 2, 256, 0, stream>>>(f1,      f2,      wd, w2h, bb, f3);

    final_kernel<<<NB, 64, 0, stream>>>(f3, out_W1, out_b1, out_W2, out_b2, (float*)d_out);
}

// Round 3
// 5202.951 us; speedup vs baseline: 1.0034x; 1.0034x over previous
//
#include <hip/hip_runtime.h>
#include <math.h>

#define NB 256      // events
#define NSV 64
#define NTRK 512
#define NPFC 512
#define KNN 8
#define HD 32

__device__ __forceinline__ float elu_f(float x) {
    return x > 0.f ? x : __expf(x) - 1.f;
}

// ---------------- encoder: out = elu(elu(x@W1+b1)@W2+b2) ----------------
// 32 nodes per block (4 iterations of 8), weights staged once.
template<int FIN>
__global__ __launch_bounds__(256) void encode_kernel(
    const float* __restrict__ x, const float* __restrict__ W1, const float* __restrict__ b1,
    const float* __restrict__ W2, const float* __restrict__ b2,
    float* __restrict__ out, int n_nodes)
{
    __shared__ float sW1[FIN * 32];
    __shared__ float sW2[32 * 32];
    __shared__ float sb1[32], sb2[32];
    __shared__ float sx[8][FIN];
    __shared__ float sh[8][32];
    int tid = threadIdx.x;
    for (int i = tid; i < FIN * 32; i += 256) sW1[i] = W1[i];
    for (int i = tid; i < 32 * 32; i += 256) sW2[i] = W2[i];
    if (tid < 32) { sb1[tid] = b1[tid]; sb2[tid] = b2[tid]; }
    int ln = tid >> 5, c = tid & 31;
    for (int it = 0; it < 4; it++) {
        int node0 = blockIdx.x * 32 + it * 8;
        __syncthreads();
        for (int i = tid; i < 8 * FIN; i += 256) {
            int nn = i / FIN, f = i - nn * FIN;
            int node = node0 + nn;
            sx[nn][f] = (node < n_nodes) ? x[(size_t)node * FIN + f] : 0.f;
        }
        __syncthreads();
        float h = sb1[c];
#pragma unroll
        for (int f = 0; f < FIN; f++) h = fmaf(sx[ln][f], sW1[f * 32 + c], h);
        h = elu_f(h);
        sh[ln][c] = h;
        __syncthreads();
        float o = sb2[c];
#pragma unroll
        for (int k = 0; k < 32; k++) o = fmaf(sh[ln][k], sW2[k * 32 + c], o);
        o = elu_f(o);
        int node = node0 + ln;
        if (node < n_nodes) out[(size_t)node * 32 + c] = o;
    }
}

// ---------------- weight prep: Wd = W[0:32]-W[32:64], W2h = W[32:64] ----------------
__global__ void prep_w_kernel(const float* __restrict__ W, const float* __restrict__ b,
                              float* __restrict__ wd, float* __restrict__ w2h,
                              float* __restrict__ bb)
{
    int i = threadIdx.x + blockIdx.x * blockDim.x;
    if (i < 1024) {
        float lo = W[i], hi = W[1024 + i];
        wd[i] = lo - hi;
        w2h[i] = hi;
    }
    if (i < 32) bb[i] = b[i];
}

// top-8 smallest across (lane, j) candidates; tie-break on lower src index.
template<int NJ>
__device__ __forceinline__ void top8_sel(float* dv, int lane, int* sel) {
#pragma unroll
    for (int k = 0; k < KNN; k++) {
        float bv = dv[0]; int bj = 0;
#pragma unroll
        for (int j = 1; j < NJ; j++) if (dv[j] < bv) { bv = dv[j]; bj = j; }
        int bs = lane + 64 * bj;
#pragma unroll
        for (int off = 32; off >= 1; off >>= 1) {
            float ov = __shfl_down(bv, off);
            int   os = __shfl_down(bs, off);
            if (ov < bv || (ov == bv && os < bs)) { bv = ov; bs = os; }
        }
        bs = __shfl(bs, 0);
        sel[k] = bs;
#pragma unroll
        for (int j = 0; j < NJ; j++) if (bs == lane + 64 * j) dv[j] = 1e30f;
    }
}

// ---------------- edge conv: kNN(K=8) + edge MLP + max-agg ----------------
// src [B,NS,32], dst [B,512,32], out [B,512,32]
// One block = (event, half of dst). 4 waves; each wave processes 2 dst nodes
// per pass (amortizes src LDS reads). LDS: float4-quad XOR swizzle
// (quad q of row s at s*8 + (q^(s&7))) -> spreads b128 reads over all 8
// bank-groups (~12 cyc/inst, the LDS throughput floor).
// amdgpu_waves_per_eu(2,2): LDS caps us at 2 blocks/CU = 2 waves/EU anyway;
// pinning it raises the VGPR budget to 256 so the ~130-reg live set
// (wdr/w2r/nrm/dot/sel) stays in registers. Without the pin the compiler
// targeted 4 waves/EU (128 VGPRs) and spilled the read-only weight arrays,
// refilling every pass -> 4 GB/dispatch scratch reads (rounds 1-2).
template<int NS>
__global__ __launch_bounds__(256) __attribute__((amdgpu_waves_per_eu(2, 2)))
void edgeconv_kernel(
    const float* __restrict__ src, const float* __restrict__ dst,
    const float* __restrict__ Wd, const float* __restrict__ W2h,
    const float* __restrict__ bias, float* __restrict__ out)
{
    constexpr int NJ = NS / 64;
    __shared__ float4 s_src[NS * 8];
    int b  = blockIdx.x >> 1;
    int hb = blockIdx.x & 1;
    int tid = threadIdx.x;
    int lane = tid & 63;
    int wave = tid >> 6;

    const float4* src4 = (const float4*)(src + (size_t)b * NS * 32);
    for (int i = tid; i < NS * 8; i += 256) {
        int s = i >> 3, q = i & 7;
        s_src[s * 8 + (q ^ (s & 7))] = src4[i];
    }
    __syncthreads();

    int c = lane & 31;
    float wdr[32], w2r[32];
#pragma unroll
    for (int d = 0; d < 32; d++) { wdr[d] = Wd[d * 32 + c]; w2r[d] = W2h[d * 32 + c]; }
    float bc = bias[c];
    int hsel = lane >> 5;

    // per-lane row norms
    float nrm[NJ];
#pragma unroll
    for (int j = 0; j < NJ; j++) {
        int s = lane + 64 * j;
        float a = 0.f;
#pragma unroll
        for (int q = 0; q < 8; q++) {
            float4 v = s_src[s * 8 + (q ^ (s & 7))];
            a = fmaf(v.x, v.x, a); a = fmaf(v.y, v.y, a);
            a = fmaf(v.z, v.z, a); a = fmaf(v.w, v.w, a);
        }
        nrm[j] = a;
    }

    for (int t0 = wave * 2; t0 < 256; t0 += 8) {
        int tA = hb * 256 + t0;
        int tB = tA + 1;
        const float4* xiA = (const float4*)(dst + ((size_t)b * 512 + tA) * 32);
        const float4* xiB = xiA + 8;

        float dotA[NJ], dotB[NJ];
#pragma unroll
        for (int j = 0; j < NJ; j++) { dotA[j] = 0.f; dotB[j] = 0.f; }
        float baseA = bc, baseB = bc;

#pragma unroll
        for (int q = 0; q < 8; q++) {
            float4 a4 = xiA[q];
            float4 b4 = xiB[q];
            baseA = fmaf(a4.x, wdr[q*4+0], baseA); baseA = fmaf(a4.y, wdr[q*4+1], baseA);
            baseA = fmaf(a4.z, wdr[q*4+2], baseA); baseA = fmaf(a4.w, wdr[q*4+3], baseA);
            baseB = fmaf(b4.x, wdr[q*4+0], baseB); baseB = fmaf(b4.y, wdr[q*4+1], baseB);
            baseB = fmaf(b4.z, wdr[q*4+2], baseB); baseB = fmaf(b4.w, wdr[q*4+3], baseB);
#pragma unroll
            for (int j = 0; j < NJ; j++) {
                int s = lane + 64 * j;
                float4 v = s_src[s * 8 + (q ^ (s & 7))];
                dotA[j] = fmaf(a4.x, v.x, dotA[j]); dotA[j] = fmaf(a4.y, v.y, dotA[j]);
                dotA[j] = fmaf(a4.z, v.z, dotA[j]); dotA[j] = fmaf(a4.w, v.w, dotA[j]);
                dotB[j] = fmaf(b4.x, v.x, dotB[j]); dotB[j] = fmaf(b4.y, v.y, dotB[j]);
                dotB[j] = fmaf(b4.z, v.z, dotB[j]); dotB[j] = fmaf(b4.w, v.w, dotB[j]);
            }
        }
        float dvA[NJ], dvB[NJ];
#pragma unroll
        for (int j = 0; j < NJ; j++) {
            dvA[j] = nrm[j] - 2.f * dotA[j];
            dvB[j] = nrm[j] - 2.f * dotB[j];
        }

        int selA[KNN], selB[KNN];
        top8_sel<NJ>(dvA, lane, selA);
        top8_sel<NJ>(dvB, lane, selB);

        // edge MLP + max-agg, dst A (half-waves split neighbor pairs; LDS
        // reads are 2-address broadcasts -> near-free)
        {
            float mx = -1e30f;
#pragma unroll
            for (int p = 0; p < 4; p++) {
                int r = hsel ? selA[2*p+1] : selA[2*p];
                float acc = baseA;
#pragma unroll
                for (int q = 0; q < 8; q++) {
                    float4 v = s_src[r * 8 + (q ^ (r & 7))];
                    acc = fmaf(v.x, w2r[q*4+0], acc); acc = fmaf(v.y, w2r[q*4+1], acc);
                    acc = fmaf(v.z, w2r[q*4+2], acc); acc = fmaf(v.w, w2r[q*4+3], acc);
                }
                mx = fmaxf(mx, elu_f(acc));
            }
            mx = fmaxf(mx, __shfl_xor(mx, 32));
            if (lane < 32) out[((size_t)b * 512 + tA) * 32 + c] = mx;
        }
        // edge MLP + max-agg, dst B
        {
            float mx = -1e30f;
#pragma unroll
            for (int p = 0; p < 4; p++) {
                int r = hsel ? selB[2*p+1] : selB[2*p];
                float acc = baseB;
#pragma unroll
                for (int q = 0; q < 8; q++) {
                    float4 v = s_src[r * 8 + (q ^ (r & 7))];
                    acc = fmaf(v.x, w2r[q*4+0], acc); acc = fmaf(v.y, w2r[q*4+1], acc);
                    acc = fmaf(v.z, w2r[q*4+2], acc); acc = fmaf(v.w, w2r[q*4+3], acc);
                }
                mx = fmaxf(mx, elu_f(acc));
            }
            mx = fmaxf(mx, __shfl_xor(mx, 32));
            if (lane < 32) out[((size_t)b * 512 + tB) * 32 + c] = mx;
        }
    }
}

// ---------------- mean pool + out MLP + sigmoid + arange ----------------
__global__ __launch_bounds__(64) void final_kernel(
    const float* __restrict__ f3,
    const float* __restrict__ W1, const float* __restrict__ b1,
    const float* __restrict__ W2, const float* __restrict__ b2,
    float* __restrict__ outp)
{
    int b = blockIdx.x;
    int lane = threadIdx.x;
    int c = lane & 31, hh = lane >> 5;
    const float* base = f3 + (size_t)b * 512 * 32;
    float s = 0.f;
    for (int r = hh; r < 512; r += 2) s += base[r * 32 + c];
    s += __shfl_xor(s, 32);
    float pooled = s * (1.0f / 512.0f);
    __shared__ float sp[32];
    __shared__ float sh1[32];
    if (lane < 32) sp[c] = pooled;
    __syncthreads();
    if (lane < 32) {
        float h = b1[c];
#pragma unroll
        for (int d = 0; d < 32; d++) h = fmaf(sp[d], W1[d * 32 + c], h);
        sh1[c] = elu_f(h);
    }
    __syncthreads();
    if (lane == 0) {
        float o = b2[0];
#pragma unroll
        for (int d = 0; d < 32; d++) o = fmaf(sh1[d], W2[d], o);
        o = 1.f / (1.f + __expf(-o));
        outp[b] = o;                 // output 0: sigmoid [B,1]
        outp[NB + b] = (float)b;     // output 1: arange(B) read as float
    }
}

extern "C" void kernel_launch(void* const* d_in, const int* in_sizes, int n_in,
                              void* d_out, int out_size, void* d_ws, size_t ws_size,
                              hipStream_t stream) {
    const float* x_sv  = (const float*)d_in[0];
    const float* x_trk = (const float*)d_in[1];
    const float* x_pfc = (const float*)d_in[2];
    const float* sv_W1  = (const float*)d_in[6];
    const float* sv_b1  = (const float*)d_in[7];
    const float* sv_W2  = (const float*)d_in[8];
    const float* sv_b2  = (const float*)d_in[9];
    const float* trk_W1 = (const float*)d_in[10];
    const float* trk_b1 = (const float*)d_in[11];
    const float* trk_W2 = (const float*)d_in[12];
    const float* trk_b2 = (const float*)d_in[13];
    const float* pfc_W1 = (const float*)d_in[14];
    const float* pfc_b1 = (const float*)d_in[15];
    const float* pfc_W2 = (const float*)d_in[16];
    const float* pfc_b2 = (const float*)d_in[17];
    const float* conv_W = (const float*)d_in[18];
    const float* conv_b = (const float*)d_in[19];
    const float* out_W1 = (const float*)d_in[20];
    const float* out_b1 = (const float*)d_in[21];
    const float* out_W2 = (const float*)d_in[22];
    const float* out_b2 = (const float*)d_in[23];

    float* ws = (float*)d_ws;
    const size_t SV_E  = (size_t)NB * NSV * HD;
    const size_t TRK_E = (size_t)NB * NTRK * HD;
    float* sv_enc  = ws;
    float* trk_enc = sv_enc + SV_E;
    float* pfc_enc = trk_enc + TRK_E;
    float* f1      = pfc_enc + TRK_E;
    float* f2      = f1 + TRK_E;
    float* wd      = f2 + TRK_E;
    float* w2h     = wd + 1024;
    float* bb      = w2h + 1024;
    float* f3      = trk_enc;  // trk_enc dead after conv2 -> reuse

    prep_w_kernel<<<1, 1024, 0, stream>>>(conv_W, conv_b, wd, w2h, bb);

    encode_kernel<14><<<(NB * NSV) / 32, 256, 0, stream>>>(x_sv, sv_W1, sv_b1, sv_W2, sv_b2, sv_enc, NB * NSV);
    encode_kernel<30><<<(NB * NTRK) / 32, 256, 0, stream>>>(x_trk, trk_W1, trk_b1, trk_W2, trk_b2, trk_enc, NB * NTRK);
    encode_kernel<10><<<(NB * NPFC) / 32, 256, 0, stream>>>(x_pfc, pfc_W1, pfc_b1, pfc_W2, pfc_b2, pfc_enc, NB * NPFC);

    edgeconv_kernel<64> <<<NB * 2, 256, 0, stream>>>(sv_enc,  trk_enc, wd, w2h, bb, f1);
    edgeconv_kernel<512><<<NB * 2, 256, 0, stream>>>(pfc_enc, trk_enc, wd, w2h, bb, f2);
    edgeconv_kernel<512><<<NB * 2, 256, 0, stream>>>(f1,      f2,      wd, w2h, bb, f3);

    final_kernel<<<NB, 64, 0, stream>>>(f3, out_W1, out_b1, out_W2, out_b2, (float*)d_out);
}

// Round 4
// 2389.606 us; speedup vs baseline: 2.1848x; 2.1773x over previous
//
#include <hip/hip_runtime.h>
#include <math.h>

#define NB 256      // events
#define NSV 64
#define NTRK 512
#define NPFC 512
#define KNN 8
#define HD 32

__device__ __forceinline__ float elu_f(float x) {
    return x > 0.f ? x : __expf(x) - 1.f;
}

// ---------------- encoder: out = elu(elu(x@W1+b1)@W2+b2) ----------------
template<int FIN>
__global__ __launch_bounds__(256) void encode_kernel(
    const float* __restrict__ x, const float* __restrict__ W1, const float* __restrict__ b1,
    const float* __restrict__ W2, const float* __restrict__ b2,
    float* __restrict__ out, int n_nodes)
{
    __shared__ float sW1[FIN * 32];
    __shared__ float sW2[32 * 32];
    __shared__ float sb1[32], sb2[32];
    __shared__ float sx[8][FIN];
    __shared__ float sh[8][32];
    int tid = threadIdx.x;
    for (int i = tid; i < FIN * 32; i += 256) sW1[i] = W1[i];
    for (int i = tid; i < 32 * 32; i += 256) sW2[i] = W2[i];
    if (tid < 32) { sb1[tid] = b1[tid]; sb2[tid] = b2[tid]; }
    int ln = tid >> 5, c = tid & 31;
    for (int it = 0; it < 4; it++) {
        int node0 = blockIdx.x * 32 + it * 8;
        __syncthreads();
        for (int i = tid; i < 8 * FIN; i += 256) {
            int nn = i / FIN, f = i - nn * FIN;
            int node = node0 + nn;
            sx[nn][f] = (node < n_nodes) ? x[(size_t)node * FIN + f] : 0.f;
        }
        __syncthreads();
        float h = sb1[c];
#pragma unroll
        for (int f = 0; f < FIN; f++) h = fmaf(sx[ln][f], sW1[f * 32 + c], h);
        h = elu_f(h);
        sh[ln][c] = h;
        __syncthreads();
        float o = sb2[c];
#pragma unroll
        for (int k = 0; k < 32; k++) o = fmaf(sh[ln][k], sW2[k * 32 + c], o);
        o = elu_f(o);
        int node = node0 + ln;
        if (node < n_nodes) out[(size_t)node * 32 + c] = o;
    }
}

// ---------------- weight prep: Wd = W[0:32]-W[32:64], W2h = W[32:64] ----------------
__global__ void prep_w_kernel(const float* __restrict__ W, const float* __restrict__ b,
                              float* __restrict__ wd, float* __restrict__ w2h,
                              float* __restrict__ bb)
{
    int i = threadIdx.x + blockIdx.x * blockDim.x;
    if (i < 1024) {
        float lo = W[i], hi = W[1024 + i];
        wd[i] = lo - hi;
        w2h[i] = hi;
    }
    if (i < 32) bb[i] = b[i];
}

// ---------------- kNN kernel: distances + top-8 -> idx_out [B,512,8] ----------
// One block = (event, half of dst). 4 waves; each wave processes 4 dst/pass.
// LDS: src rows float4-quad XOR-swizzled (quad q of row s at s*8+(q^(s&7))).
// Live regs ~75 (dot[4][NJ]=32, nrm[NJ], transients) -> fits 128, no spill.
template<int NS>
__global__ __launch_bounds__(256) void knn_kernel(
    const float* __restrict__ src, const float* __restrict__ dst,
    int* __restrict__ idx_out)
{
    constexpr int NJ = NS / 64;
    __shared__ float4 s_src[NS * 8];
    int b  = blockIdx.x >> 1;
    int hb = blockIdx.x & 1;
    int tid = threadIdx.x;
    int lane = tid & 63;
    int wave = tid >> 6;

    const float4* src4 = (const float4*)(src + (size_t)b * NS * 32);
    for (int i = tid; i < NS * 8; i += 256) {
        int s = i >> 3, q = i & 7;
        s_src[s * 8 + (q ^ (s & 7))] = src4[i];
    }
    __syncthreads();

    // per-lane row norms (same fma chain as validated rounds -> bit-exact kNN)
    float nrm[NJ];
#pragma unroll
    for (int j = 0; j < NJ; j++) {
        int s = lane + 64 * j;
        float a = 0.f;
#pragma unroll
        for (int q = 0; q < 8; q++) {
            float4 v = s_src[s * 8 + (q ^ (s & 7))];
            a = fmaf(v.x, v.x, a); a = fmaf(v.y, v.y, a);
            a = fmaf(v.z, v.z, a); a = fmaf(v.w, v.w, a);
        }
        nrm[j] = a;
    }

    for (int t0 = wave * 4; t0 < 256; t0 += 16) {
        int t = hb * 256 + t0;
        const float4* xi4 = (const float4*)(dst + ((size_t)b * 512 + t) * 32);

        float dot[4][NJ];
#pragma unroll
        for (int s = 0; s < 4; s++)
#pragma unroll
            for (int j = 0; j < NJ; j++) dot[s][j] = 0.f;

#pragma unroll
        for (int q = 0; q < 8; q++) {
            float4 x0 = xi4[q];
            float4 x1 = xi4[8 + q];
            float4 x2 = xi4[16 + q];
            float4 x3 = xi4[24 + q];
#pragma unroll
            for (int j = 0; j < NJ; j++) {
                int s = lane + 64 * j;
                float4 v = s_src[s * 8 + (q ^ (s & 7))];
                dot[0][j] = fmaf(x0.x, v.x, dot[0][j]); dot[0][j] = fmaf(x0.y, v.y, dot[0][j]);
                dot[0][j] = fmaf(x0.z, v.z, dot[0][j]); dot[0][j] = fmaf(x0.w, v.w, dot[0][j]);
                dot[1][j] = fmaf(x1.x, v.x, dot[1][j]); dot[1][j] = fmaf(x1.y, v.y, dot[1][j]);
                dot[1][j] = fmaf(x1.z, v.z, dot[1][j]); dot[1][j] = fmaf(x1.w, v.w, dot[1][j]);
                dot[2][j] = fmaf(x2.x, v.x, dot[2][j]); dot[2][j] = fmaf(x2.y, v.y, dot[2][j]);
                dot[2][j] = fmaf(x2.z, v.z, dot[2][j]); dot[2][j] = fmaf(x2.w, v.w, dot[2][j]);
                dot[3][j] = fmaf(x3.x, v.x, dot[3][j]); dot[3][j] = fmaf(x3.y, v.y, dot[3][j]);
                dot[3][j] = fmaf(x3.z, v.z, dot[3][j]); dot[3][j] = fmaf(x3.w, v.w, dot[3][j]);
            }
        }

#pragma unroll
        for (int s = 0; s < 4; s++) {
            float dv[NJ];
#pragma unroll
            for (int j = 0; j < NJ; j++) dv[j] = nrm[j] - 2.f * dot[s][j];
            size_t ebase = ((size_t)b * 512 + t + s) * 8;
#pragma unroll
            for (int k = 0; k < KNN; k++) {
                float bv = dv[0]; int bj = 0;
#pragma unroll
                for (int j = 1; j < NJ; j++) if (dv[j] < bv) { bv = dv[j]; bj = j; }
                int bs = lane + 64 * bj;
#pragma unroll
                for (int off = 32; off >= 1; off >>= 1) {
                    float ov = __shfl_down(bv, off);
                    int   os = __shfl_down(bs, off);
                    if (ov < bv || (ov == bv && os < bs)) { bv = ov; bs = os; }
                }
                bs = __shfl(bs, 0);
                if (lane == 0) idx_out[ebase + k] = bs;
#pragma unroll
                for (int j = 0; j < NJ; j++) if (bs == lane + 64 * j) dv[j] = 1e30f;
            }
        }
    }
}

// ---------------- edge-MLP kernel: gather + MLP + max-agg ----------------
// One block = (event, half of dst). 4 waves; one dst per wave pass. Lane c
// owns output column c (both half-waves); half-waves split neighbor pairs.
// Live regs ~85 (weights 64 + sel 8 + acc) -> fits 128, no spill.
template<int NS>
__global__ __launch_bounds__(256) void emlp_kernel(
    const float* __restrict__ src, const float* __restrict__ dst,
    const int* __restrict__ idx,
    const float* __restrict__ Wd, const float* __restrict__ W2h,
    const float* __restrict__ bias, float* __restrict__ out)
{
    __shared__ float4 s_src[NS * 8];
    int b  = blockIdx.x >> 1;
    int hb = blockIdx.x & 1;
    int tid = threadIdx.x;
    int lane = tid & 63;
    int wave = tid >> 6;

    const float4* src4 = (const float4*)(src + (size_t)b * NS * 32);
    for (int i = tid; i < NS * 8; i += 256) {
        int s = i >> 3, q = i & 7;
        s_src[s * 8 + (q ^ (s & 7))] = src4[i];
    }
    __syncthreads();

    int c = lane & 31;
    int hsel = lane >> 5;
    float wdr[32], w2r[32];
#pragma unroll
    for (int d = 0; d < 32; d++) { wdr[d] = Wd[d * 32 + c]; w2r[d] = W2h[d * 32 + c]; }
    float bc = bias[c];

    for (int t0 = wave; t0 < 256; t0 += 4) {
        int t = hb * 256 + t0;
        const float4* xi4 = (const float4*)(dst + ((size_t)b * 512 + t) * 32);
        const int4* sp = (const int4*)(idx + ((size_t)b * 512 + t) * 8);
        int4 s0 = sp[0];
        int4 s1 = sp[1];

        float base = bc;
#pragma unroll
        for (int q = 0; q < 8; q++) {
            float4 a4 = xi4[q];
            base = fmaf(a4.x, wdr[q*4+0], base); base = fmaf(a4.y, wdr[q*4+1], base);
            base = fmaf(a4.z, wdr[q*4+2], base); base = fmaf(a4.w, wdr[q*4+3], base);
        }

        int rows[8] = { s0.x, s0.y, s0.z, s0.w, s1.x, s1.y, s1.z, s1.w };
        float mx = -1e30f;
#pragma unroll
        for (int p = 0; p < 4; p++) {
            int r = hsel ? rows[2*p+1] : rows[2*p];
            float acc = base;
#pragma unroll
            for (int q = 0; q < 8; q++) {
                float4 v = s_src[r * 8 + (q ^ (r & 7))];
                acc = fmaf(v.x, w2r[q*4+0], acc); acc = fmaf(v.y, w2r[q*4+1], acc);
                acc = fmaf(v.z, w2r[q*4+2], acc); acc = fmaf(v.w, w2r[q*4+3], acc);
            }
            mx = fmaxf(mx, elu_f(acc));
        }
        mx = fmaxf(mx, __shfl_xor(mx, 32));
        if (lane < 32) out[((size_t)b * 512 + t) * 32 + c] = mx;
    }
}

// ---------------- mean pool + out MLP + sigmoid + arange ----------------
__global__ __launch_bounds__(64) void final_kernel(
    const float* __restrict__ f3,
    const float* __restrict__ W1, const float* __restrict__ b1,
    const float* __restrict__ W2, const float* __restrict__ b2,
    float* __restrict__ outp)
{
    int b = blockIdx.x;
    int lane = threadIdx.x;
    int c = lane & 31, hh = lane >> 5;
    const float* base = f3 + (size_t)b * 512 * 32;
    float s = 0.f;
    for (int r = hh; r < 512; r += 2) s += base[r * 32 + c];
    s += __shfl_xor(s, 32);
    float pooled = s * (1.0f / 512.0f);
    __shared__ float sp[32];
    __shared__ float sh1[32];
    if (lane < 32) sp[c] = pooled;
    __syncthreads();
    if (lane < 32) {
        float h = b1[c];
#pragma unroll
        for (int d = 0; d < 32; d++) h = fmaf(sp[d], W1[d * 32 + c], h);
        sh1[c] = elu_f(h);
    }
    __syncthreads();
    if (lane == 0) {
        float o = b2[0];
#pragma unroll
        for (int d = 0; d < 32; d++) o = fmaf(sh1[d], W2[d], o);
        o = 1.f / (1.f + __expf(-o));
        outp[b] = o;                 // output 0: sigmoid [B,1]
        outp[NB + b] = (float)b;     // output 1: arange(B) read as float
    }
}

extern "C" void kernel_launch(void* const* d_in, const int* in_sizes, int n_in,
                              void* d_out, int out_size, void* d_ws, size_t ws_size,
                              hipStream_t stream) {
    const float* x_sv  = (const float*)d_in[0];
    const float* x_trk = (const float*)d_in[1];
    const float* x_pfc = (const float*)d_in[2];
    const float* sv_W1  = (const float*)d_in[6];
    const float* sv_b1  = (const float*)d_in[7];
    const float* sv_W2  = (const float*)d_in[8];
    const float* sv_b2  = (const float*)d_in[9];
    const float* trk_W1 = (const float*)d_in[10];
    const float* trk_b1 = (const float*)d_in[11];
    const float* trk_W2 = (const float*)d_in[12];
    const float* trk_b2 = (const float*)d_in[13];
    const float* pfc_W1 = (const float*)d_in[14];
    const float* pfc_b1 = (const float*)d_in[15];
    const float* pfc_W2 = (const float*)d_in[16];
    const float* pfc_b2 = (const float*)d_in[17];
    const float* conv_W = (const float*)d_in[18];
    const float* conv_b = (const float*)d_in[19];
    const float* out_W1 = (const float*)d_in[20];
    const float* out_b1 = (const float*)d_in[21];
    const float* out_W2 = (const float*)d_in[22];
    const float* out_b2 = (const float*)d_in[23];

    float* ws = (float*)d_ws;
    const size_t SV_E  = (size_t)NB * NSV * HD;
    const size_t TRK_E = (size_t)NB * NTRK * HD;
    float* sv_enc  = ws;
    float* trk_enc = sv_enc + SV_E;
    float* pfc_enc = trk_enc + TRK_E;
    float* f1      = pfc_enc + TRK_E;
    float* f2      = f1 + TRK_E;
    float* wd      = f2 + TRK_E;
    float* w2h     = wd + 1024;
    float* bb      = w2h + 1024;
    int*   knn_idx = (int*)(bb + 64);          // [B,512,8] = 1M ints
    float* f3      = trk_enc;  // trk_enc dead after conv2 -> reuse

    prep_w_kernel<<<1, 1024, 0, stream>>>(conv_W, conv_b, wd, w2h, bb);

    encode_kernel<14><<<(NB * NSV) / 32, 256, 0, stream>>>(x_sv, sv_W1, sv_b1, sv_W2, sv_b2, sv_enc, NB * NSV);
    encode_kernel<30><<<(NB * NTRK) / 32, 256, 0, stream>>>(x_trk, trk_W1, trk_b1, trk_W2, trk_b2, trk_enc, NB * NTRK);
    encode_kernel<10><<<(NB * NPFC) / 32, 256, 0, stream>>>(x_pfc, pfc_W1, pfc_b1, pfc_W2, pfc_b2, pfc_enc, NB * NPFC);

    // conv1: sv -> trk
    knn_kernel<64>  <<<NB * 2, 256, 0, stream>>>(sv_enc, trk_enc, knn_idx);
    emlp_kernel<64> <<<NB * 2, 256, 0, stream>>>(sv_enc, trk_enc, knn_idx, wd, w2h, bb, f1);
    // conv2: pfc -> trk
    knn_kernel<512> <<<NB * 2, 256, 0, stream>>>(pfc_enc, trk_enc, knn_idx);
    emlp_kernel<512><<<NB * 2, 256, 0, stream>>>(pfc_enc, trk_enc, knn_idx, wd, w2h, bb, f2);
    // conv3: f1 -> f2
    knn_kernel<512> <<<NB * 2, 256, 0, stream>>>(f1, f2, knn_idx);
    emlp_kernel<512><<<NB * 2, 256, 0, stream>>>(f1, f2, knn_idx, wd, w2h, bb, f3);

    final_kernel<<<NB, 64, 0, stream>>>(f3, out_W1, out_b1, out_W2, out_b2, (float*)d_out);
}

// Round 5
// 881.731 us; speedup vs baseline: 5.9212x; 2.7101x over previous
//
#include <hip/hip_runtime.h>
#include <math.h>

#define NB 256      // events
#define NSV 64
#define NTRK 512
#define NPFC 512
#define KNN 8
#define HD 32

__device__ __forceinline__ float elu_f(float x) {
    return x > 0.f ? x : __expf(x) - 1.f;
}

// ---------------- encoder: out = elu(elu(x@W1+b1)@W2+b2) ----------------
template<int FIN>
__global__ __launch_bounds__(256) void encode_kernel(
    const float* __restrict__ x, const float* __restrict__ W1, const float* __restrict__ b1,
    const float* __restrict__ W2, const float* __restrict__ b2,
    float* __restrict__ out, int n_nodes)
{
    __shared__ float sW1[FIN * 32];
    __shared__ float sW2[32 * 32];
    __shared__ float sb1[32], sb2[32];
    __shared__ float sx[8][FIN];
    __shared__ float sh[8][32];
    int tid = threadIdx.x;
    for (int i = tid; i < FIN * 32; i += 256) sW1[i] = W1[i];
    for (int i = tid; i < 32 * 32; i += 256) sW2[i] = W2[i];
    if (tid < 32) { sb1[tid] = b1[tid]; sb2[tid] = b2[tid]; }
    int ln = tid >> 5, c = tid & 31;
    for (int it = 0; it < 4; it++) {
        int node0 = blockIdx.x * 32 + it * 8;
        __syncthreads();
        for (int i = tid; i < 8 * FIN; i += 256) {
            int nn = i / FIN, f = i - nn * FIN;
            int node = node0 + nn;
            sx[nn][f] = (node < n_nodes) ? x[(size_t)node * FIN + f] : 0.f;
        }
        __syncthreads();
        float h = sb1[c];
#pragma unroll
        for (int f = 0; f < FIN; f++) h = fmaf(sx[ln][f], sW1[f * 32 + c], h);
        h = elu_f(h);
        sh[ln][c] = h;
        __syncthreads();
        float o = sb2[c];
#pragma unroll
        for (int k = 0; k < 32; k++) o = fmaf(sh[ln][k], sW2[k * 32 + c], o);
        o = elu_f(o);
        int node = node0 + ln;
        if (node < n_nodes) out[(size_t)node * 32 + c] = o;
    }
}

// ---------------- weight prep: Wd = W[0:32]-W[32:64], W2h = W[32:64] ----------------
__global__ void prep_w_kernel(const float* __restrict__ W, const float* __restrict__ b,
                              float* __restrict__ wd, float* __restrict__ w2h,
                              float* __restrict__ bb)
{
    int i = threadIdx.x + blockIdx.x * blockDim.x;
    if (i < 1024) {
        float lo = W[i], hi = W[1024 + i];
        wd[i] = lo - hi;
        w2h[i] = hi;
    }
    if (i < 32) bb[i] = b[i];
}

// ---------------- kNN kernel: lanes = dst nodes, per-lane top-8 ----------
// One block = (event, half of dst): 4 waves x 64 lanes = 256 dst nodes, one
// per lane. Src rows staged in LDS row-major; the scan loop reads each src
// row with a WAVE-UNIFORM address -> pure broadcast, conflict-free, no
// swizzle needed. Selection is a per-lane branchless sorted insertion
// (strict < + ascending src scan preserves the lower-index tie-break of
// stable top_k). No cross-lane ops at all — this removes round 4's
// latency-bound shfl-butterfly argmin (772 us for NS=64 AND NS=512 alike).
template<int NS>
__global__ __launch_bounds__(256) void knn_kernel(
    const float* __restrict__ src, const float* __restrict__ dst,
    int* __restrict__ idx_out)
{
    __shared__ float4 s_src[NS * 8];
    __shared__ float  s_nrm[NS];
    int b  = blockIdx.x >> 1;
    int hb = blockIdx.x & 1;
    int tid = threadIdx.x;
    int lane = tid & 63;
    int wave = tid >> 6;

    const float4* src4 = (const float4*)(src + (size_t)b * NS * 32);
    for (int i = tid; i < NS * 8; i += 256) s_src[i] = src4[i];
    __syncthreads();
    // norms, ascending-d fma chain (same chain as validated rounds).
    // (64-way bank aliasing here; one-time ~4K cyc, irrelevant)
    for (int s = tid; s < NS; s += 256) {
        float a = 0.f;
#pragma unroll
        for (int q = 0; q < 8; q++) {
            float4 v = s_src[s * 8 + q];
            a = fmaf(v.x, v.x, a); a = fmaf(v.y, v.y, a);
            a = fmaf(v.z, v.z, a); a = fmaf(v.w, v.w, a);
        }
        s_nrm[s] = a;
    }
    __syncthreads();

    int t = hb * 256 + wave * 64 + lane;
    const float4* xi4 = (const float4*)(dst + ((size_t)b * 512 + t) * 32);
    float xd[32];
#pragma unroll
    for (int q = 0; q < 8; q++) {
        float4 v = xi4[q];
        xd[q*4+0] = v.x; xd[q*4+1] = v.y; xd[q*4+2] = v.z; xd[q*4+3] = v.w;
    }

    float val[KNN]; int idx[KNN];
#pragma unroll
    for (int k = 0; k < KNN; k++) { val[k] = 3.0e38f; idx[k] = 0; }

    // scan 2 src rows per iteration (independent fma trees for ILP)
    for (int s = 0; s < NS; s += 2) {
        float a0 = 0.f, a1 = 0.f, a2 = 0.f, a3 = 0.f;
        float b0 = 0.f, b1_ = 0.f, b2 = 0.f, b3 = 0.f;
#pragma unroll
        for (int q = 0; q < 8; q++) {
            float4 v = s_src[s * 8 + q];
            float4 w = s_src[s * 8 + 8 + q];
            a0 = fmaf(xd[q*4+0], v.x, a0); a1 = fmaf(xd[q*4+1], v.y, a1);
            a2 = fmaf(xd[q*4+2], v.z, a2); a3 = fmaf(xd[q*4+3], v.w, a3);
            b0 = fmaf(xd[q*4+0], w.x, b0); b1_ = fmaf(xd[q*4+1], w.y, b1_);
            b2 = fmaf(xd[q*4+2], w.z, b2); b3 = fmaf(xd[q*4+3], w.w, b3);
        }
        float dvA = s_nrm[s]     - 2.f * ((a0 + a1) + (a2 + a3));
        float dvB = s_nrm[s + 1] - 2.f * ((b0 + b1_) + (b2 + b3));
        if (dvA < val[KNN-1]) {
            bool c[KNN];
#pragma unroll
            for (int k = 0; k < KNN; k++) c[k] = dvA < val[k];
#pragma unroll
            for (int k = KNN-1; k >= 1; --k) {
                float tv = c[k-1] ? val[k-1] : dvA;
                int   ti = c[k-1] ? idx[k-1] : s;
                if (c[k]) { val[k] = tv; idx[k] = ti; }
            }
            if (c[0]) { val[0] = dvA; idx[0] = s; }
        }
        if (dvB < val[KNN-1]) {
            bool c[KNN];
#pragma unroll
            for (int k = 0; k < KNN; k++) c[k] = dvB < val[k];
#pragma unroll
            for (int k = KNN-1; k >= 1; --k) {
                float tv = c[k-1] ? val[k-1] : dvB;
                int   ti = c[k-1] ? idx[k-1] : (s + 1);
                if (c[k]) { val[k] = tv; idx[k] = ti; }
            }
            if (c[0]) { val[0] = dvB; idx[0] = s + 1; }
        }
    }

    int* op = idx_out + ((size_t)b * 512 + t) * 8;
#pragma unroll
    for (int k = 0; k < KNN; k++) op[k] = idx[k];
}

// ---------------- edge-MLP kernel: gather + MLP + max-agg ----------------
template<int NS>
__global__ __launch_bounds__(256) void emlp_kernel(
    const float* __restrict__ src, const float* __restrict__ dst,
    const int* __restrict__ idx,
    const float* __restrict__ Wd, const float* __restrict__ W2h,
    const float* __restrict__ bias, float* __restrict__ out)
{
    __shared__ float4 s_src[NS * 8];
    int b  = blockIdx.x >> 1;
    int hb = blockIdx.x & 1;
    int tid = threadIdx.x;
    int lane = tid & 63;
    int wave = tid >> 6;

    const float4* src4 = (const float4*)(src + (size_t)b * NS * 32);
    for (int i = tid; i < NS * 8; i += 256) {
        int s = i >> 3, q = i & 7;
        s_src[s * 8 + (q ^ (s & 7))] = src4[i];
    }
    __syncthreads();

    int c = lane & 31;
    int hsel = lane >> 5;
    float wdr[32], w2r[32];
#pragma unroll
    for (int d = 0; d < 32; d++) { wdr[d] = Wd[d * 32 + c]; w2r[d] = W2h[d * 32 + c]; }
    float bc = bias[c];

    for (int t0 = wave; t0 < 256; t0 += 4) {
        int t = hb * 256 + t0;
        const float4* xi4 = (const float4*)(dst + ((size_t)b * 512 + t) * 32);
        const int4* sp = (const int4*)(idx + ((size_t)b * 512 + t) * 8);
        int4 s0 = sp[0];
        int4 s1 = sp[1];

        float base = bc;
#pragma unroll
        for (int q = 0; q < 8; q++) {
            float4 a4 = xi4[q];
            base = fmaf(a4.x, wdr[q*4+0], base); base = fmaf(a4.y, wdr[q*4+1], base);
            base = fmaf(a4.z, wdr[q*4+2], base); base = fmaf(a4.w, wdr[q*4+3], base);
        }

        int rows[8] = { s0.x, s0.y, s0.z, s0.w, s1.x, s1.y, s1.z, s1.w };
        float mx = -1e30f;
#pragma unroll
        for (int p = 0; p < 4; p++) {
            int r = hsel ? rows[2*p+1] : rows[2*p];
            float acc = base;
#pragma unroll
            for (int q = 0; q < 8; q++) {
                float4 v = s_src[r * 8 + (q ^ (r & 7))];
                acc = fmaf(v.x, w2r[q*4+0], acc); acc = fmaf(v.y, w2r[q*4+1], acc);
                acc = fmaf(v.z, w2r[q*4+2], acc); acc = fmaf(v.w, w2r[q*4+3], acc);
            }
            mx = fmaxf(mx, elu_f(acc));
        }
        mx = fmaxf(mx, __shfl_xor(mx, 32));
        if (lane < 32) out[((size_t)b * 512 + t) * 32 + c] = mx;
    }
}

// ---------------- mean pool + out MLP + sigmoid + arange ----------------
__global__ __launch_bounds__(64) void final_kernel(
    const float* __restrict__ f3,
    const float* __restrict__ W1, const float* __restrict__ b1,
    const float* __restrict__ W2, const float* __restrict__ b2,
    float* __restrict__ outp)
{
    int b = blockIdx.x;
    int lane = threadIdx.x;
    int c = lane & 31, hh = lane >> 5;
    const float* base = f3 + (size_t)b * 512 * 32;
    float s = 0.f;
    for (int r = hh; r < 512; r += 2) s += base[r * 32 + c];
    s += __shfl_xor(s, 32);
    float pooled = s * (1.0f / 512.0f);
    __shared__ float sp[32];
    __shared__ float sh1[32];
    if (lane < 32) sp[c] = pooled;
    __syncthreads();
    if (lane < 32) {
        float h = b1[c];
#pragma unroll
        for (int d = 0; d < 32; d++) h = fmaf(sp[d], W1[d * 32 + c], h);
        sh1[c] = elu_f(h);
    }
    __syncthreads();
    if (lane == 0) {
        float o = b2[0];
#pragma unroll
        for (int d = 0; d < 32; d++) o = fmaf(sh1[d], W2[d], o);
        o = 1.f / (1.f + __expf(-o));
        outp[b] = o;                 // output 0: sigmoid [B,1]
        outp[NB + b] = (float)b;     // output 1: arange(B) read as float
    }
}

extern "C" void kernel_launch(void* const* d_in, const int* in_sizes, int n_in,
                              void* d_out, int out_size, void* d_ws, size_t ws_size,
                              hipStream_t stream) {
    const float* x_sv  = (const float*)d_in[0];
    const float* x_trk = (const float*)d_in[1];
    const float* x_pfc = (const float*)d_in[2];
    const float* sv_W1  = (const float*)d_in[6];
    const float* sv_b1  = (const float*)d_in[7];
    const float* sv_W2  = (const float*)d_in[8];
    const float* sv_b2  = (const float*)d_in[9];
    const float* trk_W1 = (const float*)d_in[10];
    const float* trk_b1 = (const float*)d_in[11];
    const float* trk_W2 = (const float*)d_in[12];
    const float* trk_b2 = (const float*)d_in[13];
    const float* pfc_W1 = (const float*)d_in[14];
    const float* pfc_b1 = (const float*)d_in[15];
    const float* pfc_W2 = (const float*)d_in[16];
    const float* pfc_b2 = (const float*)d_in[17];
    const float* conv_W = (const float*)d_in[18];
    const float* conv_b = (const float*)d_in[19];
    const float* out_W1 = (const float*)d_in[20];
    const float* out_b1 = (const float*)d_in[21];
    const float* out_W2 = (const float*)d_in[22];
    const float* out_b2 = (const float*)d_in[23];

    float* ws = (float*)d_ws;
    const size_t SV_E  = (size_t)NB * NSV * HD;
    const size_t TRK_E = (size_t)NB * NTRK * HD;
    float* sv_enc  = ws;
    float* trk_enc = sv_enc + SV_E;
    float* pfc_enc = trk_enc + TRK_E;
    float* f1      = pfc_enc + TRK_E;
    float* f2      = f1 + TRK_E;
    float* wd      = f2 + TRK_E;
    float* w2h     = wd + 1024;
    float* bb      = w2h + 1024;
    int*   knn_idx = (int*)(bb + 64);          // [B,512,8] = 1M ints
    float* f3      = trk_enc;  // trk_enc dead after conv2 -> reuse

    prep_w_kernel<<<1, 1024, 0, stream>>>(conv_W, conv_b, wd, w2h, bb);

    encode_kernel<14><<<(NB * NSV) / 32, 256, 0, stream>>>(x_sv, sv_W1, sv_b1, sv_W2, sv_b2, sv_enc, NB * NSV);
    encode_kernel<30><<<(NB * NTRK) / 32, 256, 0, stream>>>(x_trk, trk_W1, trk_b1, trk_W2, trk_b2, trk_enc, NB * NTRK);
    encode_kernel<10><<<(NB * NPFC) / 32, 256, 0, stream>>>(x_pfc, pfc_W1, pfc_b1, pfc_W2, pfc_b2, pfc_enc, NB * NPFC);

    // conv1: sv -> trk
    knn_kernel<64>  <<<NB * 2, 256, 0, stream>>>(sv_enc, trk_enc, knn_idx);
    emlp_kernel<64> <<<NB * 2, 256, 0, stream>>>(sv_enc, trk_enc, knn_idx, wd, w2h, bb, f1);
    // conv2: pfc -> trk
    knn_kernel<512> <<<NB * 2, 256, 0, stream>>>(pfc_enc, trk_enc, knn_idx);
    emlp_kernel<512><<<NB * 2, 256, 0, stream>>>(pfc_enc, trk_enc, knn_idx, wd, w2h, bb, f2);
    // conv3: f1 -> f2
    knn_kernel<512> <<<NB * 2, 256, 0, stream>>>(f1, f2, knn_idx);
    emlp_kernel<512><<<NB * 2, 256, 0, stream>>>(f1, f2, knn_idx, wd, w2h, bb, f3);

    final_kernel<<<NB, 64, 0, stream>>>(f3, out_W1, out_b1, out_W2, out_b2, (float*)d_out);
}